// Round 1
// baseline (79.331 us; speedup 1.0000x reference)
//
#include <hip/hip_runtime.h>
#include <cstdint>

// Problem constants (fixed by setup_inputs): B=4096, C=256, T=64, N_HEADS=4, ch=64.
// Eval gumbel path: argmax one-hot over softmax(qk/sqrt(ch)), a = v[:, argmax],
// weight_sum[b] = sum over heads of pmax * tie_count.

__global__ __launch_bounds__(256) void qkv_gumbel_attn(
    const float* __restrict__ q,
    const float* __restrict__ k,
    const float* __restrict__ v,
    float* __restrict__ out_a,
    float* __restrict__ out_ws)
{
    constexpr float SCALE = 0.35355339059327373f; // 64^-0.25, applied to q and k as in ref
    const int b   = blockIdx.x;
    const int tid = threadIdx.x;
    const int h   = tid >> 6;   // head (wave) 0..3
    const int l   = tid & 63;   // lane

    __shared__ float sq[256];
    __shared__ float sws[4];

    // Stage q for this batch, pre-scaled.
    sq[tid] = q[(size_t)b * 256 + tid] * SCALE;
    __syncthreads();

    // k-head tile is 64x64 floats, flattened: float4 index f4 = i*64 + l, i=0..15.
    // covers c = 4i + (l>>4), s = 4*(l&15) + j  (j = component 0..3).
    const int r = l >> 4;        // this lane's (c mod 4)
    const float4* __restrict__ k4 = reinterpret_cast<const float4*>(k);
    const size_t kbase = (size_t)b * 4096 + (size_t)h * 1024;

    float a0 = 0.f, a1 = 0.f, a2 = 0.f, a3 = 0.f;
#pragma unroll
    for (int i = 0; i < 16; ++i) {
        const float  qc = sq[h * 64 + 4 * i + r];           // already q*SCALE
        const float4 kv = k4[kbase + (size_t)(i * 64 + l)];
        a0 = fmaf(qc, kv.x * SCALE, a0);
        a1 = fmaf(qc, kv.y * SCALE, a1);
        a2 = fmaf(qc, kv.z * SCALE, a2);
        a3 = fmaf(qc, kv.w * SCALE, a3);
    }
    // Sum the 4 c-groups (lanes l, l^16, l^32, l^48). Results bitwise-replicated.
    a0 += __shfl_xor(a0, 16); a0 += __shfl_xor(a0, 32);
    a1 += __shfl_xor(a1, 16); a1 += __shfl_xor(a1, 32);
    a2 += __shfl_xor(a2, 16); a2 += __shfl_xor(a2, 32);
    a3 += __shfl_xor(a3, 16); a3 += __shfl_xor(a3, 32);
    // lane l now holds full logits for s = 4*(l&15)+j, replicated across r-groups.

    // Stable softmax over the 64 s-values (butterfly within 16-lane groups).
    float m = fmaxf(fmaxf(a0, a1), fmaxf(a2, a3));
#pragma unroll
    for (int off = 1; off <= 8; off <<= 1) m = fmaxf(m, __shfl_xor(m, off));

    const float e0 = expf(a0 - m), e1 = expf(a1 - m),
                e2 = expf(a2 - m), e3 = expf(a3 - m);
    float d = e0 + e1 + e2 + e3;
#pragma unroll
    for (int off = 1; off <= 8; off <<= 1) d += __shfl_xor(d, off);

    const float p0 = e0 / d, p1 = e1 / d, p2 = e2 / d, p3 = e3 / d;
    float pm = fmaxf(fmaxf(p0, p1), fmaxf(p2, p3));
#pragma unroll
    for (int off = 1; off <= 8; off <<= 1) pm = fmaxf(pm, __shfl_xor(pm, off));

    // One-hot selection with exact reference semantics (p == max(p), ties kept).
    // Ballot pattern repeats per 16-lane group; keep the first group.
    uint64_t m0 = __ballot(p0 == pm) & 0xFFFFull;
    uint64_t m1 = __ballot(p1 == pm) & 0xFFFFull;
    uint64_t m2 = __ballot(p2 == pm) & 0xFFFFull;
    uint64_t m3 = __ballot(p3 == pm) & 0xFFFFull;

    const int cnt = __popcll(m0) + __popcll(m1) + __popcll(m2) + __popcll(m3);

    // Gather selected v columns: lane l -> output channel c=l of this head.
    const float* __restrict__ vrow =
        v + (size_t)b * 16384 + (size_t)(h * 64 + l) * 64;
    float aval = 0.f;
    while (m0) { int i2 = __ffsll((unsigned long long)m0) - 1; m0 &= m0 - 1; aval += vrow[4 * i2 + 0]; }
    while (m1) { int i2 = __ffsll((unsigned long long)m1) - 1; m1 &= m1 - 1; aval += vrow[4 * i2 + 1]; }
    while (m2) { int i2 = __ffsll((unsigned long long)m2) - 1; m2 &= m2 - 1; aval += vrow[4 * i2 + 2]; }
    while (m3) { int i2 = __ffsll((unsigned long long)m3) - 1; m3 &= m3 - 1; aval += vrow[4 * i2 + 3]; }

    out_a[(size_t)b * 256 + tid] = aval;

    if (l == 0) sws[h] = pm * (float)cnt;
    __syncthreads();
    if (tid == 0) out_ws[b] = ((sws[0] + sws[1]) + sws[2]) + sws[3];
}

extern "C" void kernel_launch(void* const* d_in, const int* in_sizes, int n_in,
                              void* d_out, int out_size, void* d_ws, size_t ws_size,
                              hipStream_t stream) {
    const float* q = (const float*)d_in[0];
    const float* k = (const float*)d_in[1];
    const float* v = (const float*)d_in[2];
    float* out_a  = (float*)d_out;                       // 4096*256 floats
    float* out_ws = out_a + (size_t)4096 * 256;          // 4096 floats
    qkv_gumbel_attn<<<dim3(4096), dim3(256), 0, stream>>>(q, k, v, out_a, out_ws);
}

// Round 2
// 77.118 us; speedup vs baseline: 1.0287x; 1.0287x over previous
//
#include <hip/hip_runtime.h>
#include <cstdint>

// B=4096, C=256, T=64, N_HEADS=4, ch=64. Eval gumbel path:
// argmax one-hot over softmax(qk*scale^2), a = v[:, argmax-col] (tie-summed),
// weight_sum[b] = sum over heads of pmax * tie_count.
//
// Memory plan: k (256 MB) is the dominant stream -> stage via async
// global_load_lds (16B/lane, no VGPR cost), double-buffered per wave with
// counted vmcnt waits so 8 KB/wave stays in flight. Each wave owns one head,
// no cross-wave sync in the hot path.

typedef __attribute__((address_space(3))) void lds_t;
typedef const __attribute__((address_space(1))) void glb_t;

__global__ __launch_bounds__(256, 4) void qkv_gumbel_attn(
    const float* __restrict__ q,
    const float* __restrict__ k,
    const float* __restrict__ v,
    float* __restrict__ out_a,
    float* __restrict__ out_ws)
{
    constexpr float SCALE = 0.35355339059327373f; // 64^-0.25
    const int b   = blockIdx.x;
    const int tid = threadIdx.x;
    const int h   = tid >> 6;   // head == wave id
    const int l   = tid & 63;   // lane
    const int r4  = l >> 4;     // this lane's (c mod 4) group

    __shared__ float sk[4][2][1024];  // [wave][dbuf][quarter-head], 32 KB
    __shared__ float sq[256];
    __shared__ float sws[4];

    // q staged pre-scaled; wave-private region (no barrier needed).
    sq[tid] = q[(size_t)b * 256 + tid] * SCALE;
    asm volatile("" ::: "memory");  // pin q load + ds_write before staging issues

    // k head tile: 64x64 floats = 1024 float4. float4 idx f = I*64+l covers
    // c = 4I + (l>>4), s = 4*(l&15)+j. Round r handles I = 4r..4r+3.
    const float4* __restrict__ k4 =
        reinterpret_cast<const float4*>(k) + (size_t)b * 4096 + (size_t)h * 1024;

    // Prologue: stage round 0 into buf 0 (4 x 1KB async loads).
#pragma unroll
    for (int i = 0; i < 4; ++i) {
        __builtin_amdgcn_global_load_lds((glb_t*)(k4 + i * 64 + l),
                                         (lds_t*)&sk[h][0][i * 256], 16, 0, 0);
    }

    float a0 = 0.f, a1 = 0.f, a2 = 0.f, a3 = 0.f;
#pragma unroll
    for (int r = 0; r < 4; ++r) {
        if (r < 3) {
            // Issue next round into the other buffer BEFORE waiting (T4: counted wait).
#pragma unroll
            for (int i = 0; i < 4; ++i) {
                __builtin_amdgcn_global_load_lds(
                    (glb_t*)(k4 + (r + 1) * 256 + i * 64 + l),
                    (lds_t*)&sk[h][(r + 1) & 1][i * 256], 16, 0, 0);
            }
            asm volatile("s_waitcnt vmcnt(4)" ::: "memory"); // cur buf's 4 done
        } else {
            asm volatile("s_waitcnt vmcnt(0)" ::: "memory");
        }
        const float* __restrict__ buf = sk[h][r & 1];
#pragma unroll
        for (int i = 0; i < 4; ++i) {
            const float4 kv =
                *reinterpret_cast<const float4*>(&buf[i * 256 + 4 * l]);
            const float qc = sq[h * 64 + r * 16 + 4 * i + r4]; // q*SCALE
            a0 = fmaf(qc, kv.x * SCALE, a0);
            a1 = fmaf(qc, kv.y * SCALE, a1);
            a2 = fmaf(qc, kv.z * SCALE, a2);
            a3 = fmaf(qc, kv.w * SCALE, a3);
        }
    }

    // Reduce the 4 c-groups (lanes l, l^16, l^32, l^48) -> full logits,
    // replicated; lane l holds s = 4*(l&15)+j.
    a0 += __shfl_xor(a0, 16); a0 += __shfl_xor(a0, 32);
    a1 += __shfl_xor(a1, 16); a1 += __shfl_xor(a1, 32);
    a2 += __shfl_xor(a2, 16); a2 += __shfl_xor(a2, 32);
    a3 += __shfl_xor(a3, 16); a3 += __shfl_xor(a3, 32);

    // Stable softmax over 64 s-values (butterflies within 16-lane groups).
    float m = fmaxf(fmaxf(a0, a1), fmaxf(a2, a3));
#pragma unroll
    for (int off = 1; off <= 8; off <<= 1) m = fmaxf(m, __shfl_xor(m, off));

    const float e0 = expf(a0 - m), e1 = expf(a1 - m),
                e2 = expf(a2 - m), e3 = expf(a3 - m);
    float d = e0 + e1 + e2 + e3;
#pragma unroll
    for (int off = 1; off <= 8; off <<= 1) d += __shfl_xor(d, off);

    // p at argmax is expf(0)/d == 1.0f/d exactly; division is monotone, so
    // max_i(e_i/d) == 1.0f/d bitwise. Ties via float equality, as reference.
    const float pm = 1.0f / d;

    uint64_t m0 = __ballot(e0 / d == pm) & 0xFFFFull;
    uint64_t m1 = __ballot(e1 / d == pm) & 0xFFFFull;
    uint64_t m2 = __ballot(e2 / d == pm) & 0xFFFFull;
    uint64_t m3 = __ballot(e3 / d == pm) & 0xFFFFull;

    const int cnt = __popcll(m0) + __popcll(m1) + __popcll(m2) + __popcll(m3);

    // Gather selected v columns: lane l -> output channel c=l of this head.
    const float* __restrict__ vrow =
        v + (size_t)b * 16384 + (size_t)(h * 64 + l) * 64;
    float aval = 0.f;
    while (m0) { int s = __ffsll((unsigned long long)m0) - 1; m0 &= m0 - 1; aval += vrow[4 * s + 0]; }
    while (m1) { int s = __ffsll((unsigned long long)m1) - 1; m1 &= m1 - 1; aval += vrow[4 * s + 1]; }
    while (m2) { int s = __ffsll((unsigned long long)m2) - 1; m2 &= m2 - 1; aval += vrow[4 * s + 2]; }
    while (m3) { int s = __ffsll((unsigned long long)m3) - 1; m3 &= m3 - 1; aval += vrow[4 * s + 3]; }

    out_a[(size_t)b * 256 + tid] = aval;

    if (l == 0) sws[h] = pm * (float)cnt;
    __syncthreads();
    if (tid == 0) out_ws[b] = ((sws[0] + sws[1]) + sws[2]) + sws[3];
}

extern "C" void kernel_launch(void* const* d_in, const int* in_sizes, int n_in,
                              void* d_out, int out_size, void* d_ws, size_t ws_size,
                              hipStream_t stream) {
    const float* q = (const float*)d_in[0];
    const float* k = (const float*)d_in[1];
    const float* v = (const float*)d_in[2];
    float* out_a  = (float*)d_out;                  // 4096*256 floats
    float* out_ws = out_a + (size_t)4096 * 256;     // 4096 floats
    qkv_gumbel_attn<<<dim3(4096), dim3(256), 0, stream>>>(q, k, v, out_a, out_ws);
}